// Round 8
// baseline (61.263 us; speedup 1.0000x reference)
//
#include <hip/hip_runtime.h>
#include <math.h>

#define HW 512
#define KSZ 576                     // C*K*K = 64*9
#define NCHUNK 64                   // 8-row chunks per channel
#define WS_PART 0                   // KSZ*NCHUNK floats, layout [j][chunk]
#define WS_WMAX (KSZ * NCHUNK)      // 576 floats
#define WS_RQ   (WS_WMAX + KSZ)     // 576 floats
#define WS_SX   (WS_RQ + KSZ)       // 1 float
#define XF_OFF (64 * KSZ)           // wq = 36864 elements, xf follows

// ---------------------------------------------------------------------------
// Kernel 1 (4096 + 3 blocks):
//  blocks 0..4095: per-(channel, 8-row chunk) maxima of |input| for the 9
//  (kh,kw) validity regions -> ws[WS_PART + j*NCHUNK + chunk] (plain stores,
//  every slot written every call -> no init, deterministic). 4 float4/thread,
//  8 blocks/CU -> short latency chains hidden by TLP.
//  blocks 4096..4098: wmax[j] = max_co |wgt[co,j]|.
// ---------------------------------------------------------------------------
__global__ __launch_bounds__(256, 8) void k_pass1(const float* __restrict__ in,
                                                  const float* __restrict__ wgt,
                                                  float* __restrict__ ws) {
  const int t = threadIdx.x;
  if (blockIdx.x >= 4096) {                  // wmax tail blocks
    const int j = (blockIdx.x - 4096) * 256 + t;
    if (j < KSZ) {
      float wm = 0.f;
#pragma unroll 16
      for (int co = 0; co < 64; ++co) wm = fmaxf(wm, fabsf(wgt[co * KSZ + j]));
      ws[WS_WMAX + j] = wm;
    }
    return;
  }
  const int c = blockIdx.x >> 6;
  const int chunk = blockIdx.x & 63;
  const float4* base = reinterpret_cast<const float4*>(
      in + (size_t)c * HW * HW + (size_t)(chunk << 3) * HW);

  float4 v[4];
#pragma unroll
  for (int k = 0; k < 4; ++k) v[k] = base[k * 256 + t];   // 4 loads in flight

  const int col4 = t & 127;     // w-border lanes are static per thread
  const int tb = t >> 7;
  float aAll = 0.f, aNo0 = 0.f, aNoL = 0.f;   // all rows of chunk
  float bAll = 0.f, bNo0 = 0.f, bNoL = 0.f;   // excluding chunk's border row
#pragma unroll
  for (int k = 0; k < 4; ++k) {
    const float e0 = fabsf(v[k].x), e1 = fabsf(v[k].y),
                e2 = fabsf(v[k].z), e3 = fabsf(v[k].w);
    const float m4 = fmaxf(fmaxf(e0, e1), fmaxf(e2, e3));
    const float vNo0 = (col4 == 0)   ? fmaxf(fmaxf(e1, e2), e3) : m4; // excl w=0
    const float vNoL = (col4 == 127) ? fmaxf(fmaxf(e0, e1), e2) : m4; // excl w=511
    aAll = fmaxf(aAll, m4); aNo0 = fmaxf(aNo0, vNo0); aNoL = fmaxf(aNoL, vNoL);
    const int lrow = 2 * k + tb;
    const bool keep = !((chunk == 0 && lrow == 0) || (chunk == 63 && lrow == 7));
    if (keep) {
      bAll = fmaxf(bAll, m4); bNo0 = fmaxf(bNo0, vNo0); bNoL = fmaxf(bNoL, vNoL);
    }
  }
#pragma unroll
  for (int m = 32; m >= 1; m >>= 1) {
    aAll = fmaxf(aAll, __shfl_xor(aAll, m));
    aNo0 = fmaxf(aNo0, __shfl_xor(aNo0, m));
    aNoL = fmaxf(aNoL, __shfl_xor(aNoL, m));
    bAll = fmaxf(bAll, __shfl_xor(bAll, m));
    bNo0 = fmaxf(bNo0, __shfl_xor(bNo0, m));
    bNoL = fmaxf(bNoL, __shfl_xor(bNoL, m));
  }
  __shared__ float red[4][6];
  if ((t & 63) == 0) {
    const int wv = t >> 6;
    red[wv][0] = aAll; red[wv][1] = aNo0; red[wv][2] = aNoL;
    red[wv][3] = bAll; red[wv][4] = bNo0; red[wv][5] = bNoL;
  }
  __syncthreads();
  if (t == 0) {
    float r[6];
#pragma unroll
    for (int i = 0; i < 6; ++i)
      r[i] = fmaxf(fmaxf(red[0][i], red[1][i]), fmaxf(red[2][i], red[3][i]));
    // kw mapping: kw=0 -> w<=510 (NoL), kw=1 -> All, kw=2 -> w>=1 (No0)
    const float Aw[3] = {r[2], r[0], r[1]};
    const float Bw[3] = {r[5], r[3], r[4]};
    float* part = ws + WS_PART;
#pragma unroll
    for (int b = 0; b < 3; ++b) {
      const int j0 = c * 9 + 0 * 3 + b, j1 = c * 9 + 3 + b, j2 = c * 9 + 6 + b;
      part[j0 * NCHUNK + chunk] = (chunk == 63) ? Bw[b] : Aw[b];  // kh=0: h<=510
      part[j1 * NCHUNK + chunk] = Aw[b];                          // kh=1
      part[j2 * NCHUNK + chunk] = (chunk == 0) ? Bw[b] : Aw[b];   // kh=2: h>=1
    }
  }
}

// ---------------------------------------------------------------------------
// Kernel 2 (4 blocks x 576 thr): derive scale/sx/sw once (identical FP ops
// per block -> deterministic), write rq table + sx (block 0), and the full
// wq output (16 couts per block). All traffic is L2-resident.
// ---------------------------------------------------------------------------
__global__ __launch_bounds__(576) void k_scales(const float* __restrict__ wgt,
                                                float* __restrict__ ws,
                                                float* __restrict__ out) {
  __shared__ float red[9][2];
  __shared__ float s_sx, s_sw;
  const int j = threadIdx.x;      // 0..575

  const float4* pp = reinterpret_cast<const float4*>(ws + WS_PART + j * NCHUNK);
  float act = 0.f;
#pragma unroll
  for (int k = 0; k < NCHUNK / 4; ++k) {
    const float4 p = pp[k];
    act = fmaxf(act, fmaxf(fmaxf(p.x, p.y), fmaxf(p.z, p.w)));
  }
  const float wm = ws[WS_WMAX + j];
  float scale = sqrtf(act) / sqrtf(wm);   // alpha = 0.5
  if (scale == 0.f) scale = 1.f;

  float rx = act / scale;    // column max of |x/scale| (monotone in scale)
  float rw = wm * scale;
#pragma unroll
  for (int m = 32; m >= 1; m >>= 1) {
    rx = fmaxf(rx, __shfl_xor(rx, m));
    rw = fmaxf(rw, __shfl_xor(rw, m));
  }
  if ((j & 63) == 0) { red[j >> 6][0] = rx; red[j >> 6][1] = rw; }
  __syncthreads();
  if (j == 0) {
    float mx = red[0][0], mw = red[0][1];
    for (int i = 1; i < 9; ++i) { mx = fmaxf(mx, red[i][0]); mw = fmaxf(mw, red[i][1]); }
    s_sx = (mx > 0.f) ? (mx / 127.f) : 1.f;
    s_sw = (mw > 0.f) ? (mw / 127.f) : 1.f;
  }
  __syncthreads();
  const float sx = s_sx, sw = s_sw;

  if (blockIdx.x == 0) {
    ws[WS_RQ + j] = 1.f / (scale * sx);
    if (j == 0) ws[WS_SX] = sx;
  }

  // wq[co, kh, kw, c] = fq(w[co, c, kh, kw] * scale[j]; s_w), 16 couts/block
  const int c = j / 9;
  const int r = j - c * 9;
  const int obase = r * 64 + c;
#pragma unroll
  for (int k = 0; k < 16; ++k) {
    const int co = blockIdx.x * 16 + k;
    float u = (wgt[co * KSZ + j] * scale) / sw;
    u = fminf(fmaxf(u, -127.f), 127.f);
    out[co * KSZ + obase] = rintf(u) * sw;
  }
}

// ---------------------------------------------------------------------------
// Kernel 3 (4096 blocks x 256 thr): minimal prologue (copy rq table + sx),
// then 1-row x 64w x 64c quantize tile, interior no-clamp fast path, LDS
// transpose NCHW->NHWC. LDS ~20 KB -> ~8 blocks/CU.
// ---------------------------------------------------------------------------
__global__ __launch_bounds__(256) void k_fused(const float* __restrict__ in,
                                               const float* __restrict__ ws,
                                               float* __restrict__ out) {
  __shared__ float rq_s[KSZ];
  __shared__ float ldsT[64][68];      // [w_local][c]: writes 2-way (free),
  __shared__ float sx_s;              // b128 reads at throughput floor
  const int t = threadIdx.x;
  const int h = blockIdx.x >> 3;           // 512 rows
  const int w0 = (blockIdx.x & 7) << 6;
  const int c = t >> 2;                    // 4 threads per channel
  const int fi = t & 3;

  // ---- issue main input loads first; prologue hides under them ----
  const float4* ibase = reinterpret_cast<const float4*>(
      in + (size_t)c * HW * HW + (size_t)h * HW + w0);
  float4 v[4];
#pragma unroll
  for (int k = 0; k < 4; ++k) v[k] = ibase[fi + 4 * k];

  // ---- tiny prologue: copy rq table + sx from ws (L2-hit) ----
#pragma unroll
  for (int rep = 0; rep < 3; ++rep) {
    const int j = t + rep * 256;
    if (j < KSZ) rq_s[j] = ws[WS_RQ + j];
  }
  if (t == 0) sx_s = ws[WS_SX];
  __syncthreads();

  float rq[9];
#pragma unroll
  for (int jq = 0; jq < 9; ++jq) rq[jq] = rq_s[c * 9 + jq];
  const float sx = sx_s;
  const bool hb = (h == 0) || (h == 511);

#pragma unroll
  for (int k = 0; k < 4; ++k) {
    const float4 v4 = v[k];
    const int f4 = fi + 4 * k;
    const float vv[4] = {v4.x, v4.y, v4.z, v4.w};
#pragma unroll
    for (int i = 0; i < 4; ++i) {
      const int wl = f4 * 4 + i;
      const int w = w0 + wl;
      const float x = vv[i];
      float qs = 0.f;
#pragma unroll
      for (int jj = 0; jj < 9; ++jj) qs += rintf(x * rq[jj]);  // exact int sum
      if (hb || (w == 0) || (w == 511)) {                      // rare fix-up
        const bool hok0 = (h <= 510), hok2 = (h >= 1);
        const bool wok0 = (w <= 510), wok2 = (w >= 1);
        const bool ok[9] = {hok0 && wok0, hok0, hok0 && wok2,
                            wok0,         true, wok2,
                            hok2 && wok0, hok2, hok2 && wok2};
        qs = 0.f;
#pragma unroll
        for (int jj = 0; jj < 9; ++jj) {
          const float u = fminf(fmaxf(x * rq[jj], -127.f), 127.f);
          qs += ok[jj] ? rintf(u) : 0.f;
        }
      }
      ldsT[wl][c] = qs * sx;
    }
  }
  __syncthreads();

  float4* obase = reinterpret_cast<float4*>(
      out + XF_OFF + ((size_t)h * HW + w0) * 64);
#pragma unroll
  for (int k = 0; k < 4; ++k) {
    const int idx4 = k * 256 + t;        // 1024 float4 over [w_local][c]
    const int lw = idx4 >> 4;
    const int lc4 = idx4 & 15;
    obase[idx4] = *reinterpret_cast<const float4*>(&ldsT[lw][lc4 * 4]);
  }
}

extern "C" void kernel_launch(void* const* d_in, const int* in_sizes, int n_in,
                              void* d_out, int out_size, void* d_ws, size_t ws_size,
                              hipStream_t stream) {
  (void)in_sizes; (void)n_in; (void)out_size; (void)ws_size;
  const float* in = reinterpret_cast<const float*>(d_in[0]);   // (1,64,512,512)
  const float* wgt = reinterpret_cast<const float*>(d_in[1]);  // (64,64,3,3)
  float* out = reinterpret_cast<float*>(d_out);                // wq | xf
  float* ws = reinterpret_cast<float*>(d_ws);

  k_pass1<<<dim3(4096 + 3), dim3(256), 0, stream>>>(in, wgt, ws);
  k_scales<<<dim3(4), dim3(576), 0, stream>>>(wgt, ws, out);
  k_fused<<<dim3(4096), dim3(256), 0, stream>>>(in, ws, out);
}

// Round 10
// 48.222 us; speedup vs baseline: 1.2704x; 1.2704x over previous
//
#include <hip/hip_runtime.h>
#include <math.h>

#define HW 512
#define KSZ 576                     // C*K*K = 64*9
#define NCHUNK 16                   // 32-row chunks per channel
#define WS_PART 0                   // KSZ*NCHUNK floats, layout [j][chunk]
#define WS_WMAX (KSZ * NCHUNK)      // 576 floats
#define XF_OFF (64 * KSZ)           // wq = 36864 elements, xf follows

// ---------------------------------------------------------------------------
// Kernel 1 (1024 + 3 blocks)  [r6-proven]:
//  blocks 0..1023: per-(channel, 32-row chunk) maxima of |input| for the 9
//  (kh,kw) validity regions -> ws[WS_PART + j*NCHUNK + chunk] (plain stores,
//  every slot written every call -> no init, deterministic).
//  blocks 1024..1026: wmax[j] = max_co |wgt[co,j]|.
// ---------------------------------------------------------------------------
__global__ __launch_bounds__(256) void k_pass1(const float* __restrict__ in,
                                               const float* __restrict__ wgt,
                                               float* __restrict__ ws) {
  const int t = threadIdx.x;
  if (blockIdx.x >= 1024) {                  // wmax tail blocks
    const int j = (blockIdx.x - 1024) * 256 + t;
    if (j < KSZ) {
      float wm = 0.f;
#pragma unroll 16
      for (int co = 0; co < 64; ++co) wm = fmaxf(wm, fabsf(wgt[co * KSZ + j]));
      ws[WS_WMAX + j] = wm;
    }
    return;
  }
  const int c = blockIdx.x >> 4;
  const int chunk = blockIdx.x & 15;
  const float4* base = reinterpret_cast<const float4*>(
      in + (size_t)c * HW * HW + (size_t)(chunk << 5) * HW);

  float4 v[16];
#pragma unroll
  for (int k = 0; k < 16; ++k) v[k] = base[k * 256 + t];  // 16 loads in flight

  const int col4 = t & 127;     // w-border lanes are static per thread
  const int tb = t >> 7;
  float aAll = 0.f, aNo0 = 0.f, aNoL = 0.f;   // all rows of chunk
  float bAll = 0.f, bNo0 = 0.f, bNoL = 0.f;   // excluding chunk's border row
#pragma unroll
  for (int k = 0; k < 16; ++k) {
    const float e0 = fabsf(v[k].x), e1 = fabsf(v[k].y),
                e2 = fabsf(v[k].z), e3 = fabsf(v[k].w);
    const float m4 = fmaxf(fmaxf(e0, e1), fmaxf(e2, e3));
    const float vNo0 = (col4 == 0)   ? fmaxf(fmaxf(e1, e2), e3) : m4; // excl w=0
    const float vNoL = (col4 == 127) ? fmaxf(fmaxf(e0, e1), e2) : m4; // excl w=511
    aAll = fmaxf(aAll, m4); aNo0 = fmaxf(aNo0, vNo0); aNoL = fmaxf(aNoL, vNoL);
    const int lrow = 2 * k + tb;
    const bool keep = !((chunk == 0 && lrow == 0) || (chunk == 15 && lrow == 31));
    if (keep) {
      bAll = fmaxf(bAll, m4); bNo0 = fmaxf(bNo0, vNo0); bNoL = fmaxf(bNoL, vNoL);
    }
  }
#pragma unroll
  for (int m = 32; m >= 1; m >>= 1) {
    aAll = fmaxf(aAll, __shfl_xor(aAll, m));
    aNo0 = fmaxf(aNo0, __shfl_xor(aNo0, m));
    aNoL = fmaxf(aNoL, __shfl_xor(aNoL, m));
    bAll = fmaxf(bAll, __shfl_xor(bAll, m));
    bNo0 = fmaxf(bNo0, __shfl_xor(bNo0, m));
    bNoL = fmaxf(bNoL, __shfl_xor(bNoL, m));
  }
  __shared__ float red[4][6];
  if ((t & 63) == 0) {
    const int wv = t >> 6;
    red[wv][0] = aAll; red[wv][1] = aNo0; red[wv][2] = aNoL;
    red[wv][3] = bAll; red[wv][4] = bNo0; red[wv][5] = bNoL;
  }
  __syncthreads();
  if (t == 0) {
    float r[6];
#pragma unroll
    for (int i = 0; i < 6; ++i)
      r[i] = fmaxf(fmaxf(red[0][i], red[1][i]), fmaxf(red[2][i], red[3][i]));
    // kw mapping: kw=0 -> w<=510 (NoL), kw=1 -> All, kw=2 -> w>=1 (No0)
    const float Aw[3] = {r[2], r[0], r[1]};
    const float Bw[3] = {r[5], r[3], r[4]};
    float* part = ws + WS_PART;
#pragma unroll
    for (int b = 0; b < 3; ++b) {
      const int j0 = c * 9 + 0 * 3 + b, j1 = c * 9 + 3 + b, j2 = c * 9 + 6 + b;
      part[j0 * NCHUNK + chunk] = (chunk == 15) ? Bw[b] : Aw[b];  // kh=0: h<=510
      part[j1 * NCHUNK + chunk] = Aw[b];                          // kh=1
      part[j2 * NCHUNK + chunk] = (chunk == 0) ? Bw[b] : Aw[b];   // kh=2: h>=1
    }
  }
}

// ---------------------------------------------------------------------------
// Kernel 2 (1024 blocks x 256 thr = ONE block generation at 4/CU):
// issue row-0 loads, derive scale/sx/sw/rq once per block (hidden under the
// loads; identical FP ops per block -> deterministic), blocks 0..63 write wq,
// then 4 row-tiles of 64w x 64c each: prefetch next row, quantize (interior
// no-clamp fast path), LDS transpose NCHW->NHWC. LDS ~20 KB.
// ---------------------------------------------------------------------------
__global__ __launch_bounds__(256) void k_fused(const float* __restrict__ in,
                                               const float* __restrict__ wgt,
                                               const float* __restrict__ ws,
                                               float* __restrict__ out) {
  __shared__ float rq_s[KSZ];
  __shared__ float ldsT[64][68];      // [w_local][c], pad 68 (2-way = free)
  __shared__ float red[4][2];
  __shared__ float s_sx, s_sw;
  const int t = threadIdx.x;
  const int h0 = (blockIdx.x >> 3) << 2;   // 128 h-groups x 4 rows
  const int w0 = (blockIdx.x & 7) << 6;
  const int c = t >> 2;                    // 4 threads per channel
  const int fi = t & 3;

  // ---- issue row-0 loads first; prologue hides under them ----
  const float4* ibase = reinterpret_cast<const float4*>(
      in + (size_t)c * HW * HW + (size_t)h0 * HW + w0);
  float4 v0[4], v1[4];
#pragma unroll
  for (int k = 0; k < 4; ++k) v0[k] = ibase[fi + 4 * k];

  // ---- scale prologue (once per block; one generation -> ~2us wall) ----
  float scale_r[3];
  float rxm = 0.f, rwm = 0.f;
#pragma unroll
  for (int rep = 0; rep < 3; ++rep) {
    const int j = t + rep * 256;
    if (j < KSZ) {
      const float4* pp = reinterpret_cast<const float4*>(ws + WS_PART + j * NCHUNK);
      const float4 p0 = pp[0], p1 = pp[1], p2 = pp[2], p3 = pp[3];
      float act = fmaxf(fmaxf(fmaxf(p0.x, p0.y), fmaxf(p0.z, p0.w)),
                        fmaxf(fmaxf(p1.x, p1.y), fmaxf(p1.z, p1.w)));
      act = fmaxf(act, fmaxf(fmaxf(fmaxf(p2.x, p2.y), fmaxf(p2.z, p2.w)),
                             fmaxf(fmaxf(p3.x, p3.y), fmaxf(p3.z, p3.w))));
      const float wm = ws[WS_WMAX + j];
      float scale = sqrtf(act) / sqrtf(wm);   // alpha = 0.5
      if (scale == 0.f) scale = 1.f;
      scale_r[rep] = scale;
      rxm = fmaxf(rxm, act / scale);
      rwm = fmaxf(rwm, wm * scale);
    }
  }
#pragma unroll
  for (int m = 32; m >= 1; m >>= 1) {
    rxm = fmaxf(rxm, __shfl_xor(rxm, m));
    rwm = fmaxf(rwm, __shfl_xor(rwm, m));
  }
  if ((t & 63) == 0) { red[t >> 6][0] = rxm; red[t >> 6][1] = rwm; }
  __syncthreads();
  if (t == 0) {
    float mx = red[0][0], mw = red[0][1];
    for (int i = 1; i < 4; ++i) { mx = fmaxf(mx, red[i][0]); mw = fmaxf(mw, red[i][1]); }
    s_sx = (mx > 0.f) ? (mx / 127.f) : 1.f;
    s_sw = (mw > 0.f) ? (mw / 127.f) : 1.f;
  }
  __syncthreads();
  const float sx = s_sx, sw = s_sw;
#pragma unroll
  for (int rep = 0; rep < 3; ++rep) {
    const int j = t + rep * 256;
    if (j < KSZ) rq_s[j] = 1.f / (scale_r[rep] * sx);
  }
  __syncthreads();

  // ---- wq epilogue: blocks 0..63 each write one cout row ----
  if (blockIdx.x < 64) {
    const int co = blockIdx.x;
#pragma unroll
    for (int rep = 0; rep < 3; ++rep) {
      const int j = t + rep * 256;
      if (j < KSZ) {
        const int cc = j / 9;
        const int r = j - cc * 9;
        float u = (wgt[co * KSZ + j] * scale_r[rep]) / sw;
        u = fminf(fmaxf(u, -127.f), 127.f);
        out[co * KSZ + r * 64 + cc] = rintf(u) * sw;
      }
    }
  }

  float rq[9];
#pragma unroll
  for (int jq = 0; jq < 9; ++jq) rq[jq] = rq_s[c * 9 + jq];

  // ---- 4 row-tiles, software-pipelined loads ----
#pragma unroll
  for (int r = 0; r < 4; ++r) {
    if (r < 3) {
#pragma unroll
      for (int k = 0; k < 4; ++k) v1[k] = ibase[(r + 1) * 128 + fi + 4 * k];
    }
    const int h = h0 + r;
    const bool hb = (h == 0) || (h == 511);
#pragma unroll
    for (int k = 0; k < 4; ++k) {
      const float4 v4 = v0[k];
      const int f4 = fi + 4 * k;
      const float vv[4] = {v4.x, v4.y, v4.z, v4.w};
#pragma unroll
      for (int i = 0; i < 4; ++i) {
        const int wl = f4 * 4 + i;
        const int w = w0 + wl;
        const float x = vv[i];
        float qs = 0.f;
#pragma unroll
        for (int jj = 0; jj < 9; ++jj) qs += rintf(x * rq[jj]);  // exact int sum
        if (hb || (w == 0) || (w == 511)) {                      // rare fix-up
          const bool hok0 = (h <= 510), hok2 = (h >= 1);
          const bool wok0 = (w <= 510), wok2 = (w >= 1);
          const bool ok[9] = {hok0 && wok0, hok0, hok0 && wok2,
                              wok0,         true, wok2,
                              hok2 && wok0, hok2, hok2 && wok2};
          qs = 0.f;
#pragma unroll
          for (int jj = 0; jj < 9; ++jj) {
            const float u = fminf(fmaxf(x * rq[jj], -127.f), 127.f);
            qs += ok[jj] ? rintf(u) : 0.f;
          }
        }
        ldsT[wl][c] = qs * sx;
      }
    }
    __syncthreads();
    float4* obase = reinterpret_cast<float4*>(
        out + XF_OFF + ((size_t)h * HW + w0) * 64);
#pragma unroll
    for (int k = 0; k < 4; ++k) {
      const int idx4 = k * 256 + t;        // 1024 float4 over [w_local][c]
      const int lw = idx4 >> 4;
      const int lc4 = idx4 & 15;
      obase[idx4] = *reinterpret_cast<const float4*>(&ldsT[lw][lc4 * 4]);
    }
    __syncthreads();                       // ldsT free for next row
#pragma unroll
    for (int k = 0; k < 4; ++k) v0[k] = v1[k];
  }
}

extern "C" void kernel_launch(void* const* d_in, const int* in_sizes, int n_in,
                              void* d_out, int out_size, void* d_ws, size_t ws_size,
                              hipStream_t stream) {
  (void)in_sizes; (void)n_in; (void)out_size; (void)ws_size;
  const float* in = reinterpret_cast<const float*>(d_in[0]);   // (1,64,512,512)
  const float* wgt = reinterpret_cast<const float*>(d_in[1]);  // (64,64,3,3)
  float* out = reinterpret_cast<float*>(d_out);                // wq | xf
  float* ws = reinterpret_cast<float*>(d_ws);

  k_pass1<<<dim3(1024 + 3), dim3(256), 0, stream>>>(in, wgt, ws);
  k_fused<<<dim3(1024), dim3(256), 0, stream>>>(in, wgt, ws, out);
}